// Round 1
// baseline (1855.143 us; speedup 1.0000x reference)
//
#include <hip/hip_runtime.h>
#include <stdint.h>

// Problem constants
#define DIMN 50257
#define KN   4096
#define BN   512
#define DP   50432      // padded D = 8 * 6304
#define DCH  6304       // per-chunk d length = 197 * 32
#define NSTAGE 197
#define MARGIN_RAW 6.0f // raw-scale (= kl * D) refinement margin, ~20 sigma of bf16 noise

// ws layout (bytes). Total 60,114,944 B (~60.1 MB)
#define OFF_CROSS 0ul        // 4096*512 f32 = 8,388,608
#define OFF_ENT   8388608ul  // 4096 f32 (raw sums, not means)
#define OFF_CNT   8404992ul  // 512 i32
#define OFF_CANDK 8407040ul  // 512*16 i32
#define OFF_CANDV 8439808ul  // 512*16 f32
#define OFF_LQ16  8472576ul  // 512*50432 bf16 = 51,642,368

typedef short v8s __attribute__((ext_vector_type(8)));
typedef float v4f __attribute__((ext_vector_type(4)));

__device__ __forceinline__ unsigned short bf16_rne(float x) {
    unsigned u = __float_as_uint(x);
    u += 0x7fffu + ((u >> 16) & 1u);
    return (unsigned short)(u >> 16);
}

// ---------------- K0a: zero the accumulated regions (cross, ent, cnt) ----------------
__global__ void k_zero(float* __restrict__ p, long n) {
    long i = (long)blockIdx.x * blockDim.x + threadIdx.x;
    long stride = (long)gridDim.x * blockDim.x;
    for (; i < n; i += stride) p[i] = 0.0f;
}

// ---------------- K0b: lq16[b][d] = bf16(log(q[b][d])), zero pad d>=DIMN ----------------
__global__ void k_logq(const float* __restrict__ q, unsigned short* __restrict__ lq) {
    long i = (long)blockIdx.x * 256 + threadIdx.x;
    if (i >= (long)BN * DP) return;
    int b = (int)(i / DP);
    int d = (int)(i - (long)b * DP);
    unsigned short h = 0;
    if (d < DIMN) {
        float x = q[(long)b * DIMN + d];
        h = bf16_rne(__logf(x));
    }
    lq[i] = h;
}

// ---------------- K1: bf16 MFMA GEMM (cross += A @ lq^T) + fused exact ent ----------------
// grid 256 = 32 row-tiles x 8 D-chunks; 512 threads = 8 waves (2x4 wave grid);
// block tile 128 rows x 512 cols so A is streamed from HBM exactly once.
__global__ __launch_bounds__(512, 2) void k_gemm(
    const float* __restrict__ A, const unsigned short* __restrict__ LQ,
    float* __restrict__ cross, float* __restrict__ ent)
{
    // +8 shorts row padding -> conflict-free ds_read_b128 frag reads
    __shared__ __align__(16) unsigned short a_s[128 * 40];
    __shared__ __align__(16) unsigned short b_s[512 * 40];

    const int t    = threadIdx.x;
    const int bid  = blockIdx.x;
    const int rt   = bid >> 3;       // 0..31
    const int ch   = bid & 7;        // 0..7
    const int k0   = rt * 128;
    const int dbase = ch * DCH;

    const int lane = t & 63;
    const int w    = t >> 6;
    const int wr   = w >> 2;         // 0..1
    const int wc   = w & 3;          // 0..3
    const int aq   = lane >> 4;      // quad 0..3
    const int am   = lane & 15;

    // A staging: thread owns column ac of rows ar0+16i (i<8) -> coalesced dword loads
    const int ac  = t & 31;
    const int ar0 = t >> 5;          // 0..15
    // B staging: thread owns 16B granule (bn0+128i, bsub) -> coalesced dwordx4 loads
    const int bn0  = t >> 2;         // 0..127
    const int bsub = t & 3;

    v4f acc[4][8];
#pragma unroll
    for (int i = 0; i < 4; ++i)
#pragma unroll
        for (int j = 0; j < 8; ++j) acc[i][j] = (v4f){0.f, 0.f, 0.f, 0.f};

    float ent_acc[8];
#pragma unroll
    for (int i = 0; i < 8; ++i) ent_acc[i] = 0.f;

    // strength-reduced bases (all fit int32)
    int abase[8];
#pragma unroll
    for (int i = 0; i < 8; ++i) abase[i] = (k0 + ar0 + 16 * i) * DIMN + dbase + ac;
    int bbase[4];
#pragma unroll
    for (int i = 0; i < 4; ++i) bbase[i] = (bn0 + 128 * i) * DP + dbase + bsub * 8;

    float a_reg[8];
    v8s   b_reg[4];

    // prologue: load stage 0
    {
        const int d = dbase + ac;
#pragma unroll
        for (int i = 0; i < 8; ++i)
            a_reg[i] = (d < DIMN) ? A[abase[i]] : 0.0f;
#pragma unroll
        for (int i = 0; i < 4; ++i)
            b_reg[i] = *(const v8s*)&LQ[bbase[i]];
    }

#pragma unroll 1
    for (int s = 0; s < NSTAGE; ++s) {
        __syncthreads();
        // store staged regs -> LDS (+ exact fp32 ent accumulation on the fly)
#pragma unroll
        for (int i = 0; i < 8; ++i) {
            float av = a_reg[i];
            if (av > 0.f) ent_acc[i] += av * __logf(av);
            a_s[(ar0 + 16 * i) * 40 + ac] = bf16_rne(av);
        }
#pragma unroll
        for (int i = 0; i < 4; ++i)
            *(v8s*)&b_s[(bn0 + 128 * i) * 40 + bsub * 8] = b_reg[i];
        __syncthreads();

        // prefetch next stage into regs; flies behind the MFMA phase
        if (s + 1 < NSTAGE) {
            const int off = (s + 1) * 32;
            const int d = dbase + off + ac;
#pragma unroll
            for (int i = 0; i < 8; ++i)
                a_reg[i] = (d < DIMN) ? A[abase[i] + off] : 0.0f;
#pragma unroll
            for (int i = 0; i < 4; ++i)
                b_reg[i] = *(const v8s*)&LQ[bbase[i] + off];
        }

        // fragments + 32 MFMAs (wave tile 64x128)
        v8s aF[4], bF[8];
#pragma unroll
        for (int i = 0; i < 4; ++i)
            aF[i] = *(const v8s*)&a_s[(wr * 64 + i * 16 + am) * 40 + aq * 8];
#pragma unroll
        for (int j = 0; j < 8; ++j)
            bF[j] = *(const v8s*)&b_s[(wc * 128 + j * 16 + am) * 40 + aq * 8];
#pragma unroll
        for (int i = 0; i < 4; ++i)
#pragma unroll
            for (int j = 0; j < 8; ++j)
                acc[i][j] = __builtin_amdgcn_mfma_f32_16x16x32_bf16(aF[i], bF[j], acc[i][j], 0, 0, 0);
    }

    // epilogue: accumulate partial cross (fp32 atomics; noise << margin)
#pragma unroll
    for (int i = 0; i < 4; ++i)
#pragma unroll
        for (int j = 0; j < 8; ++j)
#pragma unroll
            for (int r = 0; r < 4; ++r) {
                int row = k0 + wr * 64 + i * 16 + aq * 4 + r;  // C: row=(lane>>4)*4+reg
                int col = wc * 128 + j * 16 + am;              // C: col=lane&15
                atomicAdd(&cross[(long)row * BN + col], acc[i][j][r]);
            }
    // ent: reduce over the 32 threads sharing each row (same half-wave), one atomic each
#pragma unroll
    for (int i = 0; i < 8; ++i) {
        float v = ent_acc[i];
#pragma unroll
        for (int m = 1; m <= 16; m <<= 1) v += __shfl_xor(v, m, 64);
        if ((lane & 31) == 0) atomicAdd(&ent[k0 + ar0 + 16 * i], v);
    }
}

// ---------------- K2: per-b approx argmin + candidate collection within margin ----------------
__global__ void k_argmin(const float* __restrict__ cross, const float* __restrict__ ent,
                         int* __restrict__ cnt, int* __restrict__ candk)
{
    __shared__ float sred[256];
    __shared__ int scnt;
    const int b = blockIdx.x;
    const int t = threadIdx.x;
    float vals[16];
    float best = 3.4e38f;
#pragma unroll
    for (int i = 0; i < 16; ++i) {
        int k = t + i * 256;
        float v = ent[k] - cross[(long)k * BN + b];   // raw kl * D
        vals[i] = v;
        best = fminf(best, v);
    }
    sred[t] = best;
    __syncthreads();
    for (int o = 128; o > 0; o >>= 1) {
        if (t < o) sred[t] = fminf(sred[t], sred[t + o]);
        __syncthreads();
    }
    if (t == 0) scnt = 0;
    __syncthreads();
    const float m1 = sred[0];
#pragma unroll
    for (int i = 0; i < 16; ++i) {
        if (vals[i] <= m1 + MARGIN_RAW) {
            int pos = atomicAdd(&scnt, 1);
            if (pos < 16) candk[b * 16 + pos] = t + i * 256;
        }
    }
    __syncthreads();
    if (t == 0) cnt[b] = min(scnt, 16);
}

// ---------------- K3: exact refinement of candidates (fp32 inputs, fp64 accumulate) ----------------
__global__ void k_refine(const float* __restrict__ A, const float* __restrict__ q,
                         const float* __restrict__ ent, const int* __restrict__ cnt,
                         const int* __restrict__ candk, float* __restrict__ candv)
{
    __shared__ double sred[256];
    const int b = blockIdx.x >> 4;
    const int j = blockIdx.x & 15;
    if (j >= cnt[b]) return;
    const int k = candk[b * 16 + j];
    const int t = threadIdx.x;
    const float* __restrict__ arow = A + (long)k * DIMN;
    const float* __restrict__ qrow = q + (long)b * DIMN;
    double sum = 0.0;
    for (int d = t; d < DIMN; d += 256)
        sum += (double)arow[d] * (double)__logf(qrow[d]);
    sred[t] = sum;
    __syncthreads();
    for (int o = 128; o > 0; o >>= 1) {
        if (t < o) sred[t] += sred[t + o];
        __syncthreads();
    }
    if (t == 0) candv[b * 16 + j] = (float)((double)ent[k] - sred[0]);
}

// ---------------- K4: lexicographic (val, k) min over candidates -> label ----------------
__global__ void k_final(const float* __restrict__ candv, const int* __restrict__ candk,
                        const int* __restrict__ cnt, const int* __restrict__ label,
                        int* __restrict__ out)
{
    int b = blockIdx.x * blockDim.x + threadIdx.x;
    if (b >= BN) return;
    int n = cnt[b];
    float bv = 3.4e38f;
    int bk = 1 << 30;
    for (int j = 0; j < n; ++j) {
        float v = candv[b * 16 + j];
        int kk = candk[b * 16 + j];
        if (v < bv || (v == bv && kk < bk)) { bv = v; bk = kk; }
    }
    out[b] = label[bk];
}

extern "C" void kernel_launch(void* const* d_in, const int* in_sizes, int n_in,
                              void* d_out, int out_size, void* d_ws, size_t ws_size,
                              hipStream_t stream)
{
    const float* q     = (const float*)d_in[0];   // (512, 50257) f32
    const float* A     = (const float*)d_in[1];   // (4096, 50257) f32
    const int*   label = (const int*)d_in[2];     // (4096,) i32
    int* out = (int*)d_out;                       // (512,) i32 labels

    char* ws = (char*)d_ws;
    float*          cross = (float*)(ws + OFF_CROSS);
    float*          ent   = (float*)(ws + OFF_ENT);
    int*            cnt   = (int*)(ws + OFF_CNT);
    int*            candk = (int*)(ws + OFF_CANDK);
    float*          candv = (float*)(ws + OFF_CANDV);
    unsigned short* lq    = (unsigned short*)(ws + OFF_LQ16);

    k_zero<<<1024, 256, 0, stream>>>((float*)ws, (long)(OFF_CANDK / 4));
    k_logq<<<(int)(((long)BN * DP + 255) / 256), 256, 0, stream>>>(q, lq);
    k_gemm<<<256, 512, 0, stream>>>(A, lq, cross, ent);
    k_argmin<<<BN, 256, 0, stream>>>(cross, ent, cnt, candk);
    k_refine<<<BN * 16, 256, 0, stream>>>(A, q, ent, cnt, candk, candv);
    k_final<<<2, 256, 0, stream>>>(candv, candk, cnt, label, out);
}

// Round 2
// 1690.684 us; speedup vs baseline: 1.0973x; 1.0973x over previous
//
#include <hip/hip_runtime.h>
#include <stdint.h>

// Problem constants
#define DIMN 50257
#define KN   4096
#define BN   512
#define DP   50432      // padded D = 8 * 6304
#define DCH  6304       // per-chunk d length = 197 * 32
#define NSTAGE 197
#define NCH  8
#define MARGIN_RAW 6.0f // raw-scale (= kl * D) refinement margin

// ws layout (bytes). Total ~118.8 MB
#define OFF_CROSS 0ul          // 8 * 4096*512 f32 slabs = 67,108,864
#define OFF_ENT   67108864ul   // 4096 f32 (raw sums)
#define OFF_CNT   67125248ul   // 512 i32
#define OFF_CANDK 67127296ul   // 512*16 i32
#define OFF_CANDV 67160064ul   // 512*16 f32
#define OFF_LQ16  67192832ul   // 512*50432 bf16

typedef short v8s __attribute__((ext_vector_type(8)));
typedef float v4f __attribute__((ext_vector_type(4)));
typedef unsigned short v4su __attribute__((ext_vector_type(4)));

__device__ __forceinline__ unsigned short bf16_rne(float x) {
    unsigned u = __float_as_uint(x);
    u += 0x7fffu + ((u >> 16) & 1u);
    return (unsigned short)(u >> 16);
}

// async global->LDS, 16 B per lane; LDS dest must be wave-uniform base (+lane*16)
__device__ __forceinline__ void lds_load16(const unsigned short* g, unsigned short* l) {
    __builtin_amdgcn_global_load_lds(
        reinterpret_cast<const unsigned int __attribute__((address_space(1)))*>(
            reinterpret_cast<uintptr_t>(g)),
        reinterpret_cast<unsigned int __attribute__((address_space(3)))*>(
            reinterpret_cast<uintptr_t>(l)),
        16, 0, 0);
}

// ---------------- K0a: zero ent + cnt ----------------
__global__ void k_zero(float* __restrict__ p, int n) {
    int i = blockIdx.x * 256 + threadIdx.x;
    if (i < n) p[i] = 0.0f;
}

// ---------------- K0b: lq16[b][d] = bf16(log(q[b][d])), zero pad d>=DIMN ----------------
__global__ void k_logq(const float* __restrict__ q, unsigned short* __restrict__ lq) {
    const int b  = blockIdx.y;
    const int d0 = (blockIdx.x * 256 + threadIdx.x) * 4;
    if (d0 >= DP) return;
    const float* __restrict__ qr = q + (long)b * DIMN;
    v4su out;
    if (d0 + 3 < DIMN) {
#pragma unroll
        for (int i = 0; i < 4; ++i) out[i] = bf16_rne(__logf(qr[d0 + i]));
    } else {
#pragma unroll
        for (int i = 0; i < 4; ++i) {
            int d = d0 + i;
            out[i] = (d < DIMN) ? bf16_rne(__logf(qr[d])) : (unsigned short)0;
        }
    }
    *(v4su*)(lq + (long)b * DP + d0) = out;
}

// ---------------- K1: bf16 MFMA GEMM (cross8[ch] = A_ch @ lq_ch^T) + fused exact ent ----------------
// grid 256 = 32 row-tiles x 8 D-chunks; 512 threads = 8 waves (2x4);
// block tile 128 rows x 512 cols: A streamed from HBM exactly once.
__global__ __launch_bounds__(512, 2) void k_gemm(
    const float* __restrict__ A, const unsigned short* __restrict__ LQ,
    float* __restrict__ cross, float* __restrict__ ent)
{
    __shared__ __align__(16) unsigned short a_s[128 * 40];      // padded rows (VALU-written)
    __shared__ __align__(16) unsigned short b_s[2][512 * 32];   // dbuf, async-written (contiguous!)

    const int t     = threadIdx.x;
    const int rt    = blockIdx.x >> 3;
    const int ch    = blockIdx.x & 7;
    const int k0    = rt * 128;
    const int dbase = ch * DCH;

    const int lane = t & 63;
    const int w    = t >> 6;
    const int wr   = w >> 2;        // 0..1
    const int wc   = w & 3;         // 0..3
    const int aq   = lane >> 4;     // 0..3
    const int am   = lane & 15;

    // A staging: thread owns col ac of rows ar0+16i
    const int ac  = t & 31;
    const int ar0 = t >> 5;
    // B async staging: wave w covers rows [w*64, w*64+64); per issue n: 16 rows
    const int brow = w * 64 + (lane >> 2);
    const int bcol = (lane & 3) * 8;

    v4f acc[4][8];
#pragma unroll
    for (int i = 0; i < 4; ++i)
#pragma unroll
        for (int j = 0; j < 8; ++j) acc[i][j] = (v4f){0.f, 0.f, 0.f, 0.f};

    float ent_acc[8];
#pragma unroll
    for (int i = 0; i < 8; ++i) ent_acc[i] = 0.f;

    int abase[8];
#pragma unroll
    for (int i = 0; i < 8; ++i) abase[i] = (k0 + ar0 + 16 * i) * DIMN + dbase + ac;

    float a_reg[8];

    // prologue: A regs stage 0; async B stage 0 -> b_s[0]
    {
        const int d = dbase + ac;
#pragma unroll
        for (int i = 0; i < 8; ++i)
            a_reg[i] = (d < DIMN) ? A[abase[i]] : 0.0f;
#pragma unroll
        for (int n = 0; n < 4; ++n)
            lds_load16(LQ + (brow + n * 16) * DP + dbase + bcol,
                       &b_s[0][w * 2048 + n * 512]);
    }

#pragma unroll 1
    for (int s = 0; s < NSTAGE; ++s) {
        __syncthreads();   // drains a_reg(s) and async B(s)
        // stage-s A: regs -> LDS bf16, + exact fp32 ent
#pragma unroll
        for (int i = 0; i < 8; ++i) {
            float av = a_reg[i];
            if (av > 0.f) ent_acc[i] += av * __logf(av);
            a_s[(ar0 + 16 * i) * 40 + ac] = bf16_rne(av);
        }
        __syncthreads();   // a_s visible

        // prefetch stage s+1 (A regs + async B); hides behind MFMA phase
        if (s + 1 < NSTAGE) {
            const int off = (s + 1) * 32;
            const int d = dbase + off + ac;
#pragma unroll
            for (int i = 0; i < 8; ++i)
                a_reg[i] = (d < DIMN) ? A[abase[i] + off] : 0.0f;
#pragma unroll
            for (int n = 0; n < 4; ++n)
                lds_load16(LQ + (brow + n * 16) * DP + dbase + off + bcol,
                           &b_s[(s + 1) & 1][w * 2048 + n * 512]);
        }

        // fragments + MFMA (wave tile 64x128), j-outer to keep bF single
        v8s aF[4];
#pragma unroll
        for (int i = 0; i < 4; ++i)
            aF[i] = *(const v8s*)&a_s[(wr * 64 + i * 16 + am) * 40 + aq * 8];
#pragma unroll
        for (int j = 0; j < 8; ++j) {
            v8s bF = *(const v8s*)&b_s[s & 1][(wc * 128 + j * 16 + am) * 32 + aq * 8];
#pragma unroll
            for (int i = 0; i < 4; ++i)
                acc[i][j] = __builtin_amdgcn_mfma_f32_16x16x32_bf16(aF[i], bF, acc[i][j], 0, 0, 0);
        }
    }

    // epilogue: plain stores into this chunk's slab
    float* __restrict__ crossC = cross + (long)ch * (KN * BN);
#pragma unroll
    for (int i = 0; i < 4; ++i)
#pragma unroll
        for (int j = 0; j < 8; ++j)
#pragma unroll
            for (int r = 0; r < 4; ++r) {
                int row = k0 + wr * 64 + i * 16 + aq * 4 + r;  // C: row=(lane>>4)*4+reg
                int col = wc * 128 + j * 16 + am;              // C: col=lane&15
                crossC[(long)row * BN + col] = acc[i][j][r];
            }
    // ent: reduce across the 32 threads sharing each row, one atomic each
#pragma unroll
    for (int i = 0; i < 8; ++i) {
        float v = ent_acc[i];
#pragma unroll
        for (int m = 1; m <= 16; m <<= 1) v += __shfl_xor(v, m, 64);
        if ((lane & 31) == 0) atomicAdd(&ent[k0 + ar0 + 16 * i], v);
    }
}

// ---------------- K2: per-b approx argmin (sum 8 slabs) + candidates within margin ----------------
__global__ void k_argmin(const float* __restrict__ cross, const float* __restrict__ ent,
                         int* __restrict__ cnt, int* __restrict__ candk)
{
    __shared__ float sred[256];
    __shared__ int scnt;
    const int b = blockIdx.x;
    const int t = threadIdx.x;
    float vals[16];
    float best = 3.4e38f;
#pragma unroll
    for (int i = 0; i < 16; ++i) {
        int k = t + i * 256;
        float v = ent[k];
        const float* cp = cross + (long)k * BN + b;
#pragma unroll
        for (int c = 0; c < 8; ++c) v -= cp[(long)c * (KN * BN)];
        vals[i] = v;
        best = fminf(best, v);
    }
    sred[t] = best;
    __syncthreads();
    for (int o = 128; o > 0; o >>= 1) {
        if (t < o) sred[t] = fminf(sred[t], sred[t + o]);
        __syncthreads();
    }
    if (t == 0) scnt = 0;
    __syncthreads();
    const float m1 = sred[0];
#pragma unroll
    for (int i = 0; i < 16; ++i) {
        if (vals[i] <= m1 + MARGIN_RAW) {
            int pos = atomicAdd(&scnt, 1);
            if (pos < 16) candk[b * 16 + pos] = t + i * 256;
        }
    }
    __syncthreads();
    if (t == 0) cnt[b] = min(scnt, 16);
}

// ---------------- K3: exact refinement (fp32 inputs, fp64 accumulate) ----------------
__global__ void k_refine(const float* __restrict__ A, const float* __restrict__ q,
                         const float* __restrict__ ent, const int* __restrict__ cnt,
                         const int* __restrict__ candk, float* __restrict__ candv)
{
    __shared__ double sred[256];
    const int b = blockIdx.x >> 4;
    const int j = blockIdx.x & 15;
    if (j >= cnt[b]) return;
    const int k = candk[b * 16 + j];
    const int t = threadIdx.x;
    const float* __restrict__ arow = A + (long)k * DIMN;
    const float* __restrict__ qrow = q + (long)b * DIMN;
    double sum = 0.0;
    for (int d = t * 4; d + 3 < DIMN; d += 1024) {
#pragma unroll
        for (int i = 0; i < 4; ++i)
            sum += (double)arow[d + i] * (double)__logf(qrow[d + i]);
    }
    if (t == 0)  // tail element 50256
        sum += (double)arow[DIMN - 1] * (double)__logf(qrow[DIMN - 1]);
    sred[t] = sum;
    __syncthreads();
    for (int o = 128; o > 0; o >>= 1) {
        if (t < o) sred[t] += sred[t + o];
        __syncthreads();
    }
    if (t == 0) candv[b * 16 + j] = (float)((double)ent[k] - sred[0]);
}

// ---------------- K4: lexicographic (val, k) min over candidates -> label ----------------
__global__ void k_final(const float* __restrict__ candv, const int* __restrict__ candk,
                        const int* __restrict__ cnt, const int* __restrict__ label,
                        int* __restrict__ out)
{
    int b = blockIdx.x * blockDim.x + threadIdx.x;
    if (b >= BN) return;
    int n = cnt[b];
    float bv = 3.4e38f;
    int bk = 1 << 30;
    for (int j = 0; j < n; ++j) {
        float v = candv[b * 16 + j];
        int kk = candk[b * 16 + j];
        if (v < bv || (v == bv && kk < bk)) { bv = v; bk = kk; }
    }
    out[b] = label[bk];
}

extern "C" void kernel_launch(void* const* d_in, const int* in_sizes, int n_in,
                              void* d_out, int out_size, void* d_ws, size_t ws_size,
                              hipStream_t stream)
{
    const float* q     = (const float*)d_in[0];   // (512, 50257) f32
    const float* A     = (const float*)d_in[1];   // (4096, 50257) f32
    const int*   label = (const int*)d_in[2];     // (4096,) i32
    int* out = (int*)d_out;                       // (512,) i32

    char* ws = (char*)d_ws;
    float*          cross = (float*)(ws + OFF_CROSS);
    float*          ent   = (float*)(ws + OFF_ENT);
    int*            cnt   = (int*)(ws + OFF_CNT);
    int*            candk = (int*)(ws + OFF_CANDK);
    float*          candv = (float*)(ws + OFF_CANDV);
    unsigned short* lq    = (unsigned short*)(ws + OFF_LQ16);

    k_zero<<<18, 256, 0, stream>>>(ent, 4608);  // ent + cnt contiguous
    k_logq<<<dim3(50, BN), 256, 0, stream>>>(q, lq);
    k_gemm<<<256, 512, 0, stream>>>(A, lq, cross, ent);
    k_argmin<<<BN, 256, 0, stream>>>(cross, ent, cnt, candk);
    k_refine<<<BN * 16, 256, 0, stream>>>(A, q, ent, cnt, candk, candv);
    k_final<<<2, 256, 0, stream>>>(candv, candk, cnt, label, out);
}